// Round 2
// baseline (1290.328 us; speedup 1.0000x reference)
//
#include <hip/hip_runtime.h>
#include <hip/hip_bf16.h>

#define MM 32
#define KK 8192
#define NN 28672

typedef _Float16 half8  __attribute__((ext_vector_type(8)));
typedef float    floatx4 __attribute__((ext_vector_type(4)));

// One wave computes a full-M (32) x 16-wide-N output tile over a K-chunk.
// act/scale/out are FLOAT32 on device (harness promotes fp16 -> fp32).
// weight is int32 (harness promotes int8 -> int32).
// KSPLIT: number of K-chunks (blockIdx.y). FINAL=1: apply scale, write fp32 out.
// FINAL=0: write fp32 partials to ws[blockIdx.y][M][N].
template <int KSPLIT, int FINAL>
__global__ __launch_bounds__(256) void gemm_kernel(
    const float* __restrict__ act,
    const int*   __restrict__ weight,
    const float* __restrict__ scale,
    float*       __restrict__ ws,
    float*       __restrict__ out)
{
    const int lane = threadIdx.x & 63;
    const int wave = threadIdx.x >> 6;
    const int col  = lane & 15;   // n within tile / m within A-row-frag
    const int quad = lane >> 4;   // k-subblock selector

    const int n0 = blockIdx.x * 64 + wave * 16 + col;   // this lane's n column
    const int kc = blockIdx.y * (KK / KSPLIT);
    const int ksteps = (KK / KSPLIT) / 32;

    floatx4 acc0 = {0.f, 0.f, 0.f, 0.f};   // rows 0..15
    floatx4 acc1 = {0.f, 0.f, 0.f, 0.f};   // rows 16..31

    // A fragment: A[m = col][k = kc + quad*8 + j], 8 contiguous fp32 = 32 B
    const float* ap0 = act + (size_t)col * KK + kc + quad * 8;
    const float* ap1 = ap0 + (size_t)16 * KK;
    // B fragment: B[k = kc + quad*8 + j][n = n0], j strided by NN
    const int* wp = weight + (size_t)(kc + quad * 8) * NN + n0;

    for (int s = 0; s < ksteps; ++s) {
        floatx4 a0lo = *(const floatx4*)(ap0);
        floatx4 a0hi = *(const floatx4*)(ap0 + 4);
        floatx4 a1lo = *(const floatx4*)(ap1);
        floatx4 a1hi = *(const floatx4*)(ap1 + 4);

        half8 a0, a1, b;
#pragma unroll
        for (int j = 0; j < 4; ++j) {
            a0[j]     = (_Float16)a0lo[j];   // exact: data originated as fp16
            a0[j + 4] = (_Float16)a0hi[j];
            a1[j]     = (_Float16)a1lo[j];
            a1[j + 4] = (_Float16)a1hi[j];
        }
#pragma unroll
        for (int j = 0; j < 8; ++j) {
            b[j] = (_Float16)wp[(size_t)j * NN];  // exact: |w| <= 127
        }

        acc0 = __builtin_amdgcn_mfma_f32_16x16x32_f16(a0, b, acc0, 0, 0, 0);
        acc1 = __builtin_amdgcn_mfma_f32_16x16x32_f16(a1, b, acc1, 0, 0, 0);

        ap0 += 32;
        ap1 += 32;
        wp  += (size_t)32 * NN;
    }

    // C/D layout: col = lane&15, row = quad*4 + reg
    if (FINAL) {
        float sc = scale[n0];
#pragma unroll
        for (int r = 0; r < 4; ++r) {
            int m0 = quad * 4 + r;
            out[(size_t)m0 * NN + n0]        = acc0[r] * sc;
            out[(size_t)(m0 + 16) * NN + n0] = acc1[r] * sc;
        }
    } else {
        float* wsb = ws + (size_t)blockIdx.y * MM * NN;
#pragma unroll
        for (int r = 0; r < 4; ++r) {
            int m0 = quad * 4 + r;
            wsb[(size_t)m0 * NN + n0]        = acc0[r];
            wsb[(size_t)(m0 + 16) * NN + n0] = acc1[r];
        }
    }
}

// Sum KSPLIT fp32 partials, apply per-column scale, emit fp32.
template <int KSPLIT>
__global__ __launch_bounds__(256) void finalize_kernel(
    const float* __restrict__ ws,
    const float* __restrict__ scale,
    float*       __restrict__ out)
{
    const int n = blockIdx.x * 256 + threadIdx.x;   // NN = 112 * 256
    const int m = blockIdx.y;
    if (n >= NN) return;

    float sum = 0.f;
#pragma unroll
    for (int c = 0; c < KSPLIT; ++c)
        sum += ws[(size_t)c * MM * NN + (size_t)m * NN + n];

    out[(size_t)m * NN + n] = sum * scale[n];
}

extern "C" void kernel_launch(void* const* d_in, const int* in_sizes, int n_in,
                              void* d_out, int out_size, void* d_ws, size_t ws_size,
                              hipStream_t stream)
{
    const float* act    = (const float*)d_in[0];
    const int*   weight = (const int*)d_in[1];
    const float* scale  = (const float*)d_in[2];
    float*       out    = (float*)d_out;

    constexpr int KSPLIT = 4;
    const size_t need = (size_t)KSPLIT * MM * NN * sizeof(float);

    if (ws_size >= need) {
        dim3 grid(NN / 64, KSPLIT);
        gemm_kernel<KSPLIT, 0><<<grid, 256, 0, stream>>>(act, weight, scale,
                                                         (float*)d_ws, out);
        dim3 fgrid(NN / 256, MM);
        finalize_kernel<KSPLIT><<<fgrid, 256, 0, stream>>>((const float*)d_ws,
                                                           scale, out);
    } else {
        // ws too small: single K-chunk, fused scale epilogue
        dim3 grid(NN / 64, 1);
        gemm_kernel<1, 1><<<grid, 256, 0, stream>>>(act, weight, scale,
                                                    nullptr, out);
    }
}

// Round 4
// 1204.633 us; speedup vs baseline: 1.0711x; 1.0711x over previous
//
#include <hip/hip_runtime.h>
#include <hip/hip_bf16.h>

#define MM 32
#define KK 8192
#define NN 28672

typedef _Float16 half8   __attribute__((ext_vector_type(8)));
typedef __fp16   fp16x2  __attribute__((ext_vector_type(2)));
typedef float    floatx4 __attribute__((ext_vector_type(4)));
typedef int      intx4   __attribute__((ext_vector_type(4)));

// ---------------- act fp32 -> fp16 pre-convert (exact: data originated fp16)
__global__ __launch_bounds__(256) void act_cvt_kernel(
    const float* __restrict__ act, __fp16* __restrict__ act16)
{
    int i = (blockIdx.x * 256 + threadIdx.x) * 4;   // MM*KK = 262144 = 256*256*4
    floatx4 v = *(const floatx4*)(act + i);
    fp16x2 lo = __builtin_amdgcn_cvt_pkrtz(v[0], v[1]);
    fp16x2 hi = __builtin_amdgcn_cvt_pkrtz(v[2], v[3]);
    __fp16* o = act16 + i;
    *(fp16x2*)(o)     = lo;
    *(fp16x2*)(o + 2) = hi;
}

// ---------------- main GEMM: LDS-staged weight tile, fp16 MFMA
// Block: 256 threads (4 waves). Tile: BN=64 n-cols, BK=128 k-rows per stage.
// Grid: (NN/64, KSPLIT). Each block covers K-chunk KK/KSPLIT = 16 stages.
// Writes fp32 partials to ws[blockIdx.y][MM][NN].
#define BN 64
#define BK 128
#define LDSTRIDE 136   /* fp16 units; 272 B rows -> ds_read_b128 is 2-way (free) */

template <int KSPLIT>
__global__ __launch_bounds__(256) void gemm_staged_kernel(
    const __fp16*   __restrict__ act16,
    const int*      __restrict__ weight,
    float*          __restrict__ ws)
{
    __shared__ __fp16 tileB[BN * LDSTRIDE];   // 17408 B

    const int t    = threadIdx.x;
    const int lane = t & 63;
    const int wave = t >> 6;
    const int col  = lane & 15;
    const int quad = lane >> 4;

    const int nblock = blockIdx.x * BN;
    const int kc     = blockIdx.y * (KK / KSPLIT);
    const int stages = (KK / KSPLIT) / BK;

    // staging role: seg = n-quad (4 ints), kg = k-group of 8 rows
    const int seg = t & 15;        // n0 = seg*4
    const int kg  = t >> 4;        // k0 = kg*8
    const int n0s = seg * 4;
    const int k0s = kg * 8;

    floatx4 acc0 = {0.f, 0.f, 0.f, 0.f};   // m = 0..15
    floatx4 acc1 = {0.f, 0.f, 0.f, 0.f};   // m = 16..31

    const int* wbase = weight + (size_t)(kc + k0s) * NN + nblock + n0s;
    // A fragments: act16[m][k], k = kc + ... ; 16B aligned (quad*8 fp16)
    const __fp16* abase = act16 + (size_t)col * KK + kc + quad * 8;

    for (int s = 0; s < stages; ++s) {
        // ---- stage: load 8 rows x 4 n ints per thread
        intx4 w[8];
#pragma unroll
        for (int i = 0; i < 8; ++i)
            w[i] = *(const intx4*)(wbase + (size_t)(s * BK + i) * NN);

        // convert + transpose 8k x 4n -> LDS [n][k] fp16
#pragma unroll
        for (int j = 0; j < 4; ++j) {
            fp16x2 p0 = __builtin_amdgcn_cvt_pkrtz((float)w[0][j], (float)w[1][j]);
            fp16x2 p1 = __builtin_amdgcn_cvt_pkrtz((float)w[2][j], (float)w[3][j]);
            fp16x2 p2 = __builtin_amdgcn_cvt_pkrtz((float)w[4][j], (float)w[5][j]);
            fp16x2 p3 = __builtin_amdgcn_cvt_pkrtz((float)w[6][j], (float)w[7][j]);
            __fp16* dst = tileB + (n0s + j) * LDSTRIDE + k0s;
            *(fp16x2*)(dst)     = p0;
            *(fp16x2*)(dst + 2) = p1;
            *(fp16x2*)(dst + 4) = p2;
            *(fp16x2*)(dst + 6) = p3;
        }
        __syncthreads();

        // ---- compute: wave handles n = nblock + wave*16 + col
        const __fp16* brow = tileB + (wave * 16 + col) * LDSTRIDE;
        const __fp16* ak   = abase + s * BK;
#pragma unroll
        for (int kb = 0; kb < BK / 32; ++kb) {
            half8 b  = *(const half8*)(brow + kb * 32 + quad * 8);
            half8 a0 = *(const half8*)(ak + kb * 32);
            half8 a1 = *(const half8*)(ak + kb * 32 + (size_t)16 * KK);
            acc0 = __builtin_amdgcn_mfma_f32_16x16x32_f16(a0, b, acc0, 0, 0, 0);
            acc1 = __builtin_amdgcn_mfma_f32_16x16x32_f16(a1, b, acc1, 0, 0, 0);
        }
        __syncthreads();
    }

    // partials: C/D layout col = lane&15, row = quad*4 + r
    float* wsb = ws + (size_t)blockIdx.y * MM * NN + nblock + wave * 16 + col;
#pragma unroll
    for (int r = 0; r < 4; ++r) {
        int m0 = quad * 4 + r;
        wsb[(size_t)m0 * NN]        = acc0[r];
        wsb[(size_t)(m0 + 16) * NN] = acc1[r];
    }
}

// ---------------- reduce KSPLIT partials, apply scale
template <int KSPLIT>
__global__ __launch_bounds__(256) void finalize_kernel(
    const float* __restrict__ ws,
    const float* __restrict__ scale,
    float*       __restrict__ out)
{
    const int n = blockIdx.x * 256 + threadIdx.x;   // NN = 112*256
    const int m = blockIdx.y;
    float sum = 0.f;
#pragma unroll
    for (int c = 0; c < KSPLIT; ++c)
        sum += ws[(size_t)c * MM * NN + (size_t)m * NN + n];
    out[(size_t)m * NN + n] = sum * scale[n];
}

// ---------------- fallback (ws too small): direct kernel, fused epilogue
__global__ __launch_bounds__(256) void gemm_direct_kernel(
    const float* __restrict__ act,
    const int*   __restrict__ weight,
    const float* __restrict__ scale,
    float*       __restrict__ out)
{
    const int lane = threadIdx.x & 63;
    const int wave = threadIdx.x >> 6;
    const int col  = lane & 15;
    const int quad = lane >> 4;
    const int n0 = blockIdx.x * 64 + wave * 16 + col;

    floatx4 acc0 = {0.f, 0.f, 0.f, 0.f};
    floatx4 acc1 = {0.f, 0.f, 0.f, 0.f};
    const float* ap0 = act + (size_t)col * KK + quad * 8;
    const float* ap1 = ap0 + (size_t)16 * KK;
    const int* wp = weight + (size_t)(quad * 8) * NN + n0;

    for (int s = 0; s < KK / 32; ++s) {
        floatx4 a0lo = *(const floatx4*)(ap0);
        floatx4 a0hi = *(const floatx4*)(ap0 + 4);
        floatx4 a1lo = *(const floatx4*)(ap1);
        floatx4 a1hi = *(const floatx4*)(ap1 + 4);
        half8 a0, a1, b;
#pragma unroll
        for (int j = 0; j < 4; ++j) {
            a0[j] = (_Float16)a0lo[j]; a0[j + 4] = (_Float16)a0hi[j];
            a1[j] = (_Float16)a1lo[j]; a1[j + 4] = (_Float16)a1hi[j];
        }
#pragma unroll
        for (int j = 0; j < 8; ++j)
            b[j] = (_Float16)wp[(size_t)j * NN];
        acc0 = __builtin_amdgcn_mfma_f32_16x16x32_f16(a0, b, acc0, 0, 0, 0);
        acc1 = __builtin_amdgcn_mfma_f32_16x16x32_f16(a1, b, acc1, 0, 0, 0);
        ap0 += 32; ap1 += 32; wp += (size_t)32 * NN;
    }
    float sc = scale[n0];
#pragma unroll
    for (int r = 0; r < 4; ++r) {
        int m0 = quad * 4 + r;
        out[(size_t)m0 * NN + n0]        = acc0[r] * sc;
        out[(size_t)(m0 + 16) * NN + n0] = acc1[r] * sc;
    }
}

extern "C" void kernel_launch(void* const* d_in, const int* in_sizes, int n_in,
                              void* d_out, int out_size, void* d_ws, size_t ws_size,
                              hipStream_t stream)
{
    const float* act    = (const float*)d_in[0];
    const int*   weight = (const int*)d_in[1];
    const float* scale  = (const float*)d_in[2];
    float*       out    = (float*)d_out;

    constexpr int KSPLIT = 4;
    const size_t partials_bytes = (size_t)KSPLIT * MM * NN * sizeof(float); // 14680064
    const size_t act16_off      = partials_bytes;                            // 16B aligned
    const size_t need           = act16_off + (size_t)MM * KK * sizeof(__fp16);

    if (ws_size >= need) {
        float*   ws_part = (float*)d_ws;
        __fp16*  act16   = (__fp16*)((char*)d_ws + act16_off);

        act_cvt_kernel<<<MM * KK / (256 * 4), 256, 0, stream>>>(act, act16);

        dim3 grid(NN / BN, KSPLIT);
        gemm_staged_kernel<KSPLIT><<<grid, 256, 0, stream>>>(act16, weight, ws_part);

        dim3 fgrid(NN / 256, MM);
        finalize_kernel<KSPLIT><<<fgrid, 256, 0, stream>>>(ws_part, scale, out);
    } else {
        gemm_direct_kernel<<<NN / 64, 256, 0, stream>>>(act, weight, scale, out);
    }
}